// Round 4
// baseline (1308.745 us; speedup 1.0000x reference)
//
#include <hip/hip_runtime.h>

typedef __attribute__((ext_vector_type(8))) short bf16x8;
typedef __attribute__((ext_vector_type(4))) float f32x4;

// ---------------------------------------------------------------------------
// f32 -> bf16 round-to-nearest-even
__device__ __forceinline__ unsigned short f2bf(float x) {
    unsigned u = __float_as_uint(x);
    u += 0x7fffu + ((u >> 16) & 1u);
    return (unsigned short)(u >> 16);
}

// Fused slice + convert + mask-zero for BOTH inputs (one launch).
__global__ void conv_kernel(const float* __restrict__ im, const int* __restrict__ iml,
                            const float* __restrict__ ss, const int* __restrict__ sl,
                            unsigned short* __restrict__ Ad, unsigned short* __restrict__ Bd)
{
    int bid = blockIdx.x;
    const float* src; const int* len; unsigned short* dst; int rawL, adj;
    if (bid < 8192) { src = im; len = iml; dst = Ad; rawL = 65; adj = -1; }
    else { bid -= 8192; src = ss; len = sl; dst = Bd; rawL = 67; adj = -3; }
    int m = bid;
    int c = threadIdx.x << 2;
    int b = m >> 6;
    int i = m & 63;
    int lim = len[b] + adj;
    float4 v;
    if (i < lim) {
        v = *(const float4*)(src + ((size_t)(b * rawL + 1 + i) << 10) + c);
    } else {
        v = make_float4(0.f, 0.f, 0.f, 0.f);
    }
    ushort4 o;
    o.x = f2bf(v.x); o.y = f2bf(v.y); o.z = f2bf(v.z); o.w = f2bf(v.w);
    *(ushort4*)(dst + ((size_t)m << 10) + c) = o;
}

// ---------------------------------------------------------------------------
__device__ __forceinline__ void gload_lds16(const void* g, void* l) {
    __builtin_amdgcn_global_load_lds((const __attribute__((address_space(1))) void*)g,
                                     (__attribute__((address_space(3))) void*)l,
                                     16, 0, 0);
}

// 256x256 tile, BK=64, 8 waves (2M x 4N), per-wave 128x64 output.
// A: LDS double-buffer (64 KiB total -> 2 blocks/CU). B: direct global->VGPR
// gathers, register double-buffered, issued one full tile ahead.
// 2 phases/tile, counted vmcnt gates: phX vmcnt(2), phY vmcnt(8). Never 0
// mid-loop. Fused wave-local reduction: aggr[b,t] = sum_j max_i C_cell.
__global__ void __launch_bounds__(512, 4) gemm_aggr_kernel(const unsigned short* __restrict__ A,
                                                           const unsigned short* __restrict__ B,
                                                           float* __restrict__ aggr)
{
    __shared__ __align__(16) unsigned short As[2][256 * 64];   // 2 x 32 KiB

    const int tid  = threadIdx.x;
    const int lane = tid & 63;
    const int wid  = tid >> 6;        // 0..7
    const int wr   = wid >> 2;        // 0..1 : 128-row half of BM
    const int wc   = wid & 3;         // 0..3 : 64-col quarter of BN
    const int tm   = blockIdx.y;      // 0..31
    const int tn   = blockIdx.x;      // 0..31

    const int r15 = lane & 15;
    const int g4  = lane >> 4;        // 0..3
    const int swz = r15 & 7;

    // A staging: 4 rounds/tile, each 64 rows x 64 cols (8 KB), 512 thr x 16 B.
    // LDS dest linear; global source chunk pre-swizzled (both-sides XOR).
    const int srow   = tid >> 3;
    const int schunk = (tid & 7) ^ (srow & 7);
    const unsigned short* gA_t = A + ((size_t)(tm * 256 + srow) << 10) + schunk * 8;

#define STAGE_A(kt, r) gload_lds16(gA_t + (((size_t)((r) * 64)) << 10) + (kt) * 64, \
                                   (char*)As[(kt) & 1] + (r) * 8192 + tid * 16)

    // B gather base: lane covers row tn*256 + wc*64 + ni*16 + r15, k-chunk g4*8.
    const unsigned short* gBbase = B + ((size_t)(tn * 256 + wc * 64 + r15) << 10) + g4 * 8;

    f32x4 acc[4][2][4];   // [32-row quadrant][mi][ni]
#pragma unroll
    for (int p = 0; p < 4; ++p)
#pragma unroll
        for (int mi = 0; mi < 2; ++mi)
#pragma unroll
            for (int ni = 0; ni < 4; ++ni)
                acc[p][mi][ni] = (f32x4){0.f, 0.f, 0.f, 0.f};

    bf16x8 bg0[4][2], bg1[4][2];

    // Prologue: B(0) gathers (8) then A(0) stages (4), order-pinned so the
    // in-flight tail at the first phX gate is exactly {A0 r2, A0 r3}.
#pragma unroll
    for (int ni = 0; ni < 4; ++ni) {
        bg0[ni][0] = *(const bf16x8*)(gBbase + ni * 16384);
        bg0[ni][1] = *(const bf16x8*)(gBbase + ni * 16384 + 32);
    }
    __builtin_amdgcn_sched_barrier(0);
    STAGE_A(0, 0); STAGE_A(0, 1);
    __builtin_amdgcn_sched_barrier(0);
    STAGE_A(0, 2); STAGE_A(0, 3);
    __builtin_amdgcn_sched_barrier(0);

    const int ch0 = (g4 ^ swz) * 16;
    const int ch1 = ((4 + g4) ^ swz) * 16;
    const int AroB = wr * 128 + r15;   // row base (rows), quadrant adds p*32+mi*16

#define TILE(KT, BGC, BGN)                                                          \
  {                                                                                 \
    const char* Ab = (const char*)As[(KT) & 1];                                     \
    /* ---------- phase X : quadrants 0,1 ---------- */                             \
    asm volatile("s_waitcnt vmcnt(2)" ::: "memory");                                \
    __builtin_amdgcn_s_barrier();                                                   \
    __builtin_amdgcn_sched_barrier(0);                                              \
    bf16x8 af[2][2][2];                                                             \
    _Pragma("unroll")                                                               \
    for (int pp = 0; pp < 2; ++pp)                                                  \
      _Pragma("unroll")                                                             \
      for (int mi = 0; mi < 2; ++mi) {                                              \
        const int Aro = (AroB + pp * 32 + mi * 16) * 128;                           \
        af[pp][mi][0] = *(const bf16x8*)(Ab + Aro + ch0);                           \
        af[pp][mi][1] = *(const bf16x8*)(Ab + Aro + ch1);                           \
      }                                                                             \
    if ((KT) < 15) {                                                                \
      const unsigned short* gBt = gBbase + ((KT) + 1) * 64;                         \
      _Pragma("unroll")                                                             \
      for (int ni = 0; ni < 4; ++ni) {                                              \
        BGN[ni][0] = *(const bf16x8*)(gBt + ni * 16384);                            \
        BGN[ni][1] = *(const bf16x8*)(gBt + ni * 16384 + 32);                       \
      }                                                                             \
    }                                                                               \
    asm volatile("s_waitcnt lgkmcnt(0)" ::: "memory");                              \
    __builtin_amdgcn_sched_barrier(0);                                              \
    __builtin_amdgcn_s_setprio(1);                                                  \
    _Pragma("unroll")                                                               \
    for (int pp = 0; pp < 2; ++pp)                                                  \
      _Pragma("unroll")                                                             \
      for (int mi = 0; mi < 2; ++mi)                                                \
        _Pragma("unroll")                                                           \
        for (int ni = 0; ni < 4; ++ni) {                                            \
          acc[pp][mi][ni] = __builtin_amdgcn_mfma_f32_16x16x32_bf16(                \
              af[pp][mi][0], BGC[ni][0], acc[pp][mi][ni], 0, 0, 0);                 \
          acc[pp][mi][ni] = __builtin_amdgcn_mfma_f32_16x16x32_bf16(                \
              af[pp][mi][1], BGC[ni][1], acc[pp][mi][ni], 0, 0, 0);                 \
        }                                                                           \
    __builtin_amdgcn_s_setprio(0);                                                  \
    /* ---------- phase Y : quadrants 2,3 ---------- */                             \
    if ((KT) < 15) { asm volatile("s_waitcnt vmcnt(8)" ::: "memory"); }             \
    else           { asm volatile("s_waitcnt vmcnt(0)" ::: "memory"); }             \
    __builtin_amdgcn_s_barrier();                                                   \
    __builtin_amdgcn_sched_barrier(0);                                              \
    _Pragma("unroll")                                                               \
    for (int pp = 0; pp < 2; ++pp)                                                  \
      _Pragma("unroll")                                                             \
      for (int mi = 0; mi < 2; ++mi) {                                              \
        const int Aro = (AroB + (2 + pp) * 32 + mi * 16) * 128;                     \
        af[pp][mi][0] = *(const bf16x8*)(Ab + Aro + ch0);                           \
        af[pp][mi][1] = *(const bf16x8*)(Ab + Aro + ch1);                           \
      }                                                                             \
    if ((KT) < 15) {                                                                \
      STAGE_A((KT) + 1, 0); STAGE_A((KT) + 1, 1);                                   \
      __builtin_amdgcn_sched_barrier(0);                                            \
      STAGE_A((KT) + 1, 2); STAGE_A((KT) + 1, 3);                                   \
    }                                                                               \
    asm volatile("s_waitcnt lgkmcnt(0)" ::: "memory");                              \
    __builtin_amdgcn_sched_barrier(0);                                              \
    __builtin_amdgcn_s_setprio(1);                                                  \
    _Pragma("unroll")                                                               \
    for (int pp = 0; pp < 2; ++pp)                                                  \
      _Pragma("unroll")                                                             \
      for (int mi = 0; mi < 2; ++mi)                                                \
        _Pragma("unroll")                                                           \
        for (int ni = 0; ni < 4; ++ni) {                                            \
          acc[2 + pp][mi][ni] = __builtin_amdgcn_mfma_f32_16x16x32_bf16(            \
              af[pp][mi][0], BGC[ni][0], acc[2 + pp][mi][ni], 0, 0, 0);             \
          acc[2 + pp][mi][ni] = __builtin_amdgcn_mfma_f32_16x16x32_bf16(            \
              af[pp][mi][1], BGC[ni][1], acc[2 + pp][mi][ni], 0, 0, 0);             \
        }                                                                           \
    __builtin_amdgcn_s_setprio(0);                                                  \
  }

    for (int kt2 = 0; kt2 < 8; ++kt2) {
        TILE(kt2 * 2,     bg0, bg1);
        TILE(kt2 * 2 + 1, bg1, bg0);
    }
#undef TILE
#undef STAGE_A

    // Fused reduction per 64x64 (b,t) cell. C/D: col=lane&15, row=(lane>>4)*4+reg.
#pragma unroll
    for (int h = 0; h < 2; ++h) {
        float cm[4];
#pragma unroll
        for (int ni = 0; ni < 4; ++ni) {
            float m = acc[h * 2][0][ni][0];
#pragma unroll
            for (int pp = 0; pp < 2; ++pp)
#pragma unroll
                for (int mi = 0; mi < 2; ++mi)
#pragma unroll
                    for (int r = 0; r < 4; ++r)
                        m = fmaxf(m, acc[h * 2 + pp][mi][ni][r]);
            m = fmaxf(m, __shfl_xor(m, 16));
            m = fmaxf(m, __shfl_xor(m, 32));
            cm[ni] = m;
        }
        float s = cm[0] + cm[1] + cm[2] + cm[3];
        s += __shfl_xor(s, 1);
        s += __shfl_xor(s, 2);
        s += __shfl_xor(s, 4);
        s += __shfl_xor(s, 8);
        if (lane == 0) {
            int b = tm * 4 + wr * 2 + h;
            int t = tn * 4 + wc;
            aggr[b * 128 + t] = s;
        }
    }
}

// ---------------------------------------------------------------------------
__global__ void loss_kernel(const float* __restrict__ aggr, float* __restrict__ out)
{
    __shared__ float red[128];
    const int x = threadIdx.x;
    const float diag = aggr[x * 128 + x];
    float mrow = 0.f, mcol = 0.f;
    for (int y = 0; y < 128; ++y) {
        if (y == x) continue;
        float a_xy = aggr[x * 128 + y];
        float a_yx = aggr[y * 128 + x];
        mrow = fmaxf(mrow, 0.2f + a_xy - diag);
        mcol = fmaxf(mcol, 0.2f + a_yx - diag);
    }
    red[x] = mrow + mcol;
    __syncthreads();
    if (x == 0) {
        float s = 0.f;
        for (int i = 0; i < 128; ++i) s += red[i];
        *out = s;
    }
}

// ---------------------------------------------------------------------------
extern "C" void kernel_launch(void* const* d_in, const int* in_sizes, int n_in,
                              void* d_out, int out_size, void* d_ws, size_t ws_size,
                              hipStream_t stream)
{
    const float* im_set = (const float*)d_in[0];
    const float* s_seq  = (const float*)d_in[1];
    const int*   im_len = (const int*)d_in[2];
    const int*   s_len  = (const int*)d_in[3];
    float* out = (float*)d_out;

    unsigned short* Abf = (unsigned short*)d_ws;                           // 16 MiB
    unsigned short* Bbf = (unsigned short*)((char*)d_ws + (16u << 20));    // 16 MiB
    float*          agg = (float*)((char*)d_ws + (32u << 20));             // 64 KiB

    conv_kernel<<<16384, 256, 0, stream>>>(im_set, im_len, s_seq, s_len, Abf, Bbf);

    gemm_aggr_kernel<<<dim3(32, 32), 512, 0, stream>>>(Abf, Bbf, agg);

    loss_kernel<<<1, 128, 0, stream>>>(agg, out);
}

// Round 5
// 310.209 us; speedup vs baseline: 4.2189x; 4.2189x over previous
//
#include <hip/hip_runtime.h>

typedef __attribute__((ext_vector_type(8))) short bf16x8;
typedef __attribute__((ext_vector_type(4))) float f32x4;

// ---------------------------------------------------------------------------
// f32 -> bf16 round-to-nearest-even
__device__ __forceinline__ unsigned short f2bf(float x) {
    unsigned u = __float_as_uint(x);
    u += 0x7fffu + ((u >> 16) & 1u);
    return (unsigned short)(u >> 16);
}

// Fused slice + convert + mask-zero for BOTH inputs (one launch).
__global__ void conv_kernel(const float* __restrict__ im, const int* __restrict__ iml,
                            const float* __restrict__ ss, const int* __restrict__ sl,
                            unsigned short* __restrict__ Ad, unsigned short* __restrict__ Bd)
{
    int bid = blockIdx.x;
    const float* src; const int* len; unsigned short* dst; int rawL, adj;
    if (bid < 8192) { src = im; len = iml; dst = Ad; rawL = 65; adj = -1; }
    else { bid -= 8192; src = ss; len = sl; dst = Bd; rawL = 67; adj = -3; }
    int m = bid;
    int c = threadIdx.x << 2;
    int b = m >> 6;
    int i = m & 63;
    int lim = len[b] + adj;
    float4 v;
    if (i < lim) {
        v = *(const float4*)(src + ((size_t)(b * rawL + 1 + i) << 10) + c);
    } else {
        v = make_float4(0.f, 0.f, 0.f, 0.f);
    }
    ushort4 o;
    o.x = f2bf(v.x); o.y = f2bf(v.y); o.z = f2bf(v.z); o.w = f2bf(v.w);
    *(ushort4*)(dst + ((size_t)m << 10) + c) = o;
}

// ---------------------------------------------------------------------------
__device__ __forceinline__ void gload_lds16(const void* g, void* l) {
    __builtin_amdgcn_global_load_lds((const __attribute__((address_space(1))) void*)g,
                                     (__attribute__((address_space(3))) void*)l,
                                     16, 0, 0);
}

// 256x256 tile, BK=64, 8 waves (2M x 4N), per-wave 128x64 output.
// B: LDS double-buffer (64 KiB), XOR-swizzled, staged 1 round/phase.
// A: direct global->VGPR per-phase fragments, 2-phase lead, parity buffers.
// Sync: 1 barrier + 1 lgkm per tile; counted vmcnt gates 4/5/5/5 (tail 4/4/4/0).
// Fused wave-local reduction: aggr[b,t] = sum_j max_i C_cell.
__global__ void __launch_bounds__(512) gemm_aggr_kernel(const unsigned short* __restrict__ A,
                                                        const unsigned short* __restrict__ B,
                                                        float* __restrict__ aggr)
{
    __shared__ __align__(16) unsigned short Bs[2][256 * 64];   // 2 x 32 KiB

    const int tid  = threadIdx.x;
    const int lane = tid & 63;
    const int wid  = tid >> 6;        // 0..7
    const int wr   = wid >> 2;        // 0..1 : 128-row half of BM
    const int wc   = wid & 3;         // 0..3 : 64-col quarter of BN
    const int tm   = blockIdx.y;      // 0..31
    const int tn   = blockIdx.x;      // 0..31

    const int r15 = lane & 15;
    const int g4  = lane >> 4;        // 0..3
    const int swz = r15 & 7;

    // B staging: 4 rounds/tile, each 64 rows x 64 cols (8 KB), 512 thr x 16 B.
    // LDS dest linear; global source chunk pre-swizzled (both-sides XOR).
    const int srow   = tid >> 3;
    const int schunk = (tid & 7) ^ (srow & 7);
    const unsigned short* gB_t = B + ((size_t)(tn * 256 + srow) << 10) + schunk * 8;

#define STAGE_B(kt, r) gload_lds16(gB_t + (((size_t)((r) * 64)) << 10) + (kt) * 64, \
                                   (char*)Bs[(kt) & 1] + (r) * 8192 + tid * 16)

    // A gather: lane covers row tm*256 + wr*128 + p*32 + mi*16 + r15, k-chunk g4*8.
    // 16 fully-consumed 64B lines per instruction; waves sharing wr dedup in L1.
    const unsigned short* gA = A + ((size_t)(tm * 256 + wr * 128 + r15) << 10) + g4 * 8;

#define LOAD_AF(AF, KT, P) do {                                                  \
    const unsigned short* ga_ = gA + (((size_t)((P) * 32)) << 10) + (KT) * 64;   \
    AF[0][0] = *(const bf16x8*)(ga_);                                            \
    AF[0][1] = *(const bf16x8*)(ga_ + 32);                                       \
    AF[1][0] = *(const bf16x8*)(ga_ + (16 << 10));                               \
    AF[1][1] = *(const bf16x8*)(ga_ + (16 << 10) + 32);                          \
} while (0)

    f32x4 acc[4][2][4];   // [32-row quadrant][mi][ni]
#pragma unroll
    for (int p = 0; p < 4; ++p)
#pragma unroll
        for (int mi = 0; mi < 2; ++mi)
#pragma unroll
            for (int ni = 0; ni < 4; ++ni)
                acc[p][mi][ni] = (f32x4){0.f, 0.f, 0.f, 0.f};

    bf16x8 afE[2][2], afO[2][2], bg[4][2];

    // Prologue, order-pinned: [B(0) r0-3] [afE = A(ph0,0)] [afO = A(ph1,0)].
    STAGE_B(0, 0); STAGE_B(0, 1); STAGE_B(0, 2); STAGE_B(0, 3);
    __builtin_amdgcn_sched_barrier(0);
    LOAD_AF(afE, 0, 0);
    __builtin_amdgcn_sched_barrier(0);
    LOAD_AF(afO, 0, 1);
    __builtin_amdgcn_sched_barrier(0);

    const int Bro = (wc * 64 + r15) * 128;       // B row byte base in slot
    const int ch0 = (g4 ^ swz) * 16;
    const int ch1 = ((4 + g4) ^ swz) * 16;

#define READ_BG(Bb)                                                         \
    _Pragma("unroll")                                                       \
    for (int ni = 0; ni < 4; ++ni) {                                        \
        bg[ni][0] = *(const bf16x8*)((Bb) + Bro + ni * 2048 + ch0);         \
        bg[ni][1] = *(const bf16x8*)((Bb) + Bro + ni * 2048 + ch1);         \
    }

#define MFMA_PHASE(P, AF)                                                   \
    __builtin_amdgcn_s_setprio(1);                                          \
    _Pragma("unroll")                                                       \
    for (int mi = 0; mi < 2; ++mi)                                          \
      _Pragma("unroll")                                                     \
      for (int ni = 0; ni < 4; ++ni) {                                      \
        acc[P][mi][ni] = __builtin_amdgcn_mfma_f32_16x16x32_bf16(           \
            AF[mi][0], bg[ni][0], acc[P][mi][ni], 0, 0, 0);                 \
        acc[P][mi][ni] = __builtin_amdgcn_mfma_f32_16x16x32_bf16(           \
            AF[mi][1], bg[ni][1], acc[P][mi][ni], 0, 0, 0);                 \
      }                                                                     \
    __builtin_amdgcn_s_setprio(0);

    for (int kt = 0; kt < 15; ++kt) {
        const char* Bb = (const char*)Bs[kt & 1];
        // ---- phase 0 : B(kt) + afE ready; newest-4 in flight = afO(ph1) ----
        asm volatile("s_waitcnt vmcnt(4)" ::: "memory");
        __builtin_amdgcn_s_barrier();
        __builtin_amdgcn_sched_barrier(0);
        READ_BG(Bb)
        asm volatile("s_waitcnt lgkmcnt(0)" ::: "memory");
        __builtin_amdgcn_sched_barrier(0);
        MFMA_PHASE(0, afE)
        STAGE_B(kt + 1, 0);
        __builtin_amdgcn_sched_barrier(0);
        LOAD_AF(afE, kt, 2);
        // ---- phase 1 ----
        asm volatile("s_waitcnt vmcnt(5)" ::: "memory");
        __builtin_amdgcn_sched_barrier(0);
        MFMA_PHASE(1, afO)
        STAGE_B(kt + 1, 1);
        __builtin_amdgcn_sched_barrier(0);
        LOAD_AF(afO, kt, 3);
        // ---- phase 2 ----
        asm volatile("s_waitcnt vmcnt(5)" ::: "memory");
        __builtin_amdgcn_sched_barrier(0);
        MFMA_PHASE(2, afE)
        STAGE_B(kt + 1, 2);
        __builtin_amdgcn_sched_barrier(0);
        LOAD_AF(afE, kt + 1, 0);
        // ---- phase 3 ----
        asm volatile("s_waitcnt vmcnt(5)" ::: "memory");
        __builtin_amdgcn_sched_barrier(0);
        MFMA_PHASE(3, afO)
        STAGE_B(kt + 1, 3);
        __builtin_amdgcn_sched_barrier(0);
        LOAD_AF(afO, kt + 1, 1);
    }
    // ---- tail tile kt = 15 (no further staging; gates 4/4/4/0) ----
    {
        const char* Bb = (const char*)Bs[1];
        asm volatile("s_waitcnt vmcnt(4)" ::: "memory");
        __builtin_amdgcn_s_barrier();
        __builtin_amdgcn_sched_barrier(0);
        READ_BG(Bb)
        asm volatile("s_waitcnt lgkmcnt(0)" ::: "memory");
        __builtin_amdgcn_sched_barrier(0);
        MFMA_PHASE(0, afE)
        LOAD_AF(afE, 15, 2);
        asm volatile("s_waitcnt vmcnt(4)" ::: "memory");
        __builtin_amdgcn_sched_barrier(0);
        MFMA_PHASE(1, afO)
        LOAD_AF(afO, 15, 3);
        asm volatile("s_waitcnt vmcnt(4)" ::: "memory");
        __builtin_amdgcn_sched_barrier(0);
        MFMA_PHASE(2, afE)
        asm volatile("s_waitcnt vmcnt(0)" ::: "memory");
        __builtin_amdgcn_sched_barrier(0);
        MFMA_PHASE(3, afO)
    }
#undef STAGE_B
#undef LOAD_AF
#undef READ_BG
#undef MFMA_PHASE

    // Fused reduction per 64x64 (b,t) cell. C/D: col=lane&15, row=(lane>>4)*4+reg.
#pragma unroll
    for (int h = 0; h < 2; ++h) {
        float cm[4];
#pragma unroll
        for (int ni = 0; ni < 4; ++ni) {
            float m = acc[h * 2][0][ni][0];
#pragma unroll
            for (int pp = 0; pp < 2; ++pp)
#pragma unroll
                for (int mi = 0; mi < 2; ++mi)
#pragma unroll
                    for (int r = 0; r < 4; ++r)
                        m = fmaxf(m, acc[h * 2 + pp][mi][ni][r]);
            m = fmaxf(m, __shfl_xor(m, 16));
            m = fmaxf(m, __shfl_xor(m, 32));
            cm[ni] = m;
        }
        float s = cm[0] + cm[1] + cm[2] + cm[3];
        s += __shfl_xor(s, 1);
        s += __shfl_xor(s, 2);
        s += __shfl_xor(s, 4);
        s += __shfl_xor(s, 8);
        if (lane == 0) {
            int b = tm * 4 + wr * 2 + h;
            int t = tn * 4 + wc;
            aggr[b * 128 + t] = s;
        }
    }
}

// ---------------------------------------------------------------------------
__global__ void loss_kernel(const float* __restrict__ aggr, float* __restrict__ out)
{
    __shared__ float red[128];
    const int x = threadIdx.x;
    const float diag = aggr[x * 128 + x];
    float mrow = 0.f, mcol = 0.f;
    for (int y = 0; y < 128; ++y) {
        if (y == x) continue;
        float a_xy = aggr[x * 128 + y];
        float a_yx = aggr[y * 128 + x];
        mrow = fmaxf(mrow, 0.2f + a_xy - diag);
        mcol = fmaxf(mcol, 0.2f + a_yx - diag);
    }
    red[x] = mrow + mcol;
    __syncthreads();
    if (x == 0) {
        float s = 0.f;
        for (int i = 0; i < 128; ++i) s += red[i];
        *out = s;
    }
}

// ---------------------------------------------------------------------------
extern "C" void kernel_launch(void* const* d_in, const int* in_sizes, int n_in,
                              void* d_out, int out_size, void* d_ws, size_t ws_size,
                              hipStream_t stream)
{
    const float* im_set = (const float*)d_in[0];
    const float* s_seq  = (const float*)d_in[1];
    const int*   im_len = (const int*)d_in[2];
    const int*   s_len  = (const int*)d_in[3];
    float* out = (float*)d_out;

    unsigned short* Abf = (unsigned short*)d_ws;                           // 16 MiB
    unsigned short* Bbf = (unsigned short*)((char*)d_ws + (16u << 20));    // 16 MiB
    float*          agg = (float*)((char*)d_ws + (32u << 20));             // 64 KiB

    conv_kernel<<<16384, 256, 0, stream>>>(im_set, im_len, s_seq, s_len, Abf, Bbf);

    gemm_aggr_kernel<<<dim3(32, 32), 512, 0, stream>>>(Abf, Bbf, agg);

    loss_kernel<<<1, 128, 0, stream>>>(agg, out);
}

// Round 6
// 141.929 us; speedup vs baseline: 9.2211x; 2.1857x over previous
//
#include <hip/hip_runtime.h>

typedef __attribute__((ext_vector_type(8))) short bf16x8;
typedef __attribute__((ext_vector_type(4))) float f32x4;

// ---------------------------------------------------------------------------
// f32 -> bf16 round-to-nearest-even
__device__ __forceinline__ unsigned short f2bf(float x) {
    unsigned u = __float_as_uint(x);
    u += 0x7fffu + ((u >> 16) & 1u);
    return (unsigned short)(u >> 16);
}

// Fused slice + convert + mask-zero for BOTH inputs (one launch).
__global__ void conv_kernel(const float* __restrict__ im, const int* __restrict__ iml,
                            const float* __restrict__ ss, const int* __restrict__ sl,
                            unsigned short* __restrict__ Ad, unsigned short* __restrict__ Bd)
{
    int bid = blockIdx.x;
    const float* src; const int* len; unsigned short* dst; int rawL, adj;
    if (bid < 8192) { src = im; len = iml; dst = Ad; rawL = 65; adj = -1; }
    else { bid -= 8192; src = ss; len = sl; dst = Bd; rawL = 67; adj = -3; }
    int m = bid;
    int c = threadIdx.x << 2;
    int b = m >> 6;
    int i = m & 63;
    int lim = len[b] + adj;
    float4 v;
    if (i < lim) {
        v = *(const float4*)(src + ((size_t)(b * rawL + 1 + i) << 10) + c);
    } else {
        v = make_float4(0.f, 0.f, 0.f, 0.f);
    }
    ushort4 o;
    o.x = f2bf(v.x); o.y = f2bf(v.y); o.z = f2bf(v.z); o.w = f2bf(v.w);
    *(ushort4*)(dst + ((size_t)m << 10) + c) = o;
}

// ---------------------------------------------------------------------------
__device__ __forceinline__ void gload_lds16(const void* g, void* l) {
    __builtin_amdgcn_global_load_lds((const __attribute__((address_space(1))) void*)g,
                                     (__attribute__((address_space(3))) void*)l,
                                     16, 0, 0);
}

// 256x256 tile, BK=64, 8 waves (2M x 4N), per-wave 128x64 output.
// A and B in double-buffered LDS (128 KiB), XOR-swizzled, zero-conflict.
// Round-3 vmcnt ledger: staging per tile {B01,B23,A02,A13}; gates vmcnt(2)@h0,
// vmcnt(4)@h1 (tail vmcnt(0)). NEW: within each gated half-tile, ALL ds_reads
// issued up front in pinned groups; compiler's counted lgkmcnt lets phase-p+1
// reads complete under phase-p's MFMA burst (LDS pipe overlaps MFMA pipe).
// Fused wave-local reduction: aggr[b,t] = sum_j max_i C_cell.
__global__ void __launch_bounds__(512) gemm_aggr_kernel(const unsigned short* __restrict__ A,
                                                        const unsigned short* __restrict__ B,
                                                        float* __restrict__ aggr)
{
    __shared__ __align__(16) unsigned short As[2][256 * 64];   // 2 x 32 KiB
    __shared__ __align__(16) unsigned short Bs[2][256 * 64];   // 2 x 32 KiB

    const int tid  = threadIdx.x;
    const int lane = tid & 63;
    const int wid  = tid >> 6;        // 0..7
    const int wr   = wid >> 2;        // 0..1 : 128-row half of BM
    const int wc   = wid & 3;         // 0..3 : 64-col quarter of BN
    const int tm   = blockIdx.y;      // 0..31
    const int tn   = blockIdx.x;      // 0..31

    const int r15 = lane & 15;
    const int g4  = lane >> 4;        // 0..3
    const int swz = r15 & 7;

    // Staging: each round = 64 rows x 64 cols (8 KB), 512 thr x 16 B.
    // LDS dest linear; global source chunk pre-swizzled (both-sides XOR).
    const int srow   = tid >> 3;
    const int schunk = (tid & 7) ^ (srow & 7);
    const unsigned short* gA_t = A + ((size_t)(tm * 256 + srow) << 10) + schunk * 8;
    const unsigned short* gB_t = B + ((size_t)(tn * 256 + srow) << 10) + schunk * 8;

#define STAGE_A(kt, r) gload_lds16(gA_t + (((size_t)((r) * 64)) << 10) + (kt) * 64, \
                                   (char*)As[(kt) & 1] + (r) * 8192 + tid * 16)
#define STAGE_B(kt, r) gload_lds16(gB_t + (((size_t)((r) * 64)) << 10) + (kt) * 64, \
                                   (char*)Bs[(kt) & 1] + (r) * 8192 + tid * 16)

    f32x4 acc[4][2][4];   // [32-row quadrant][mi][ni]
#pragma unroll
    for (int p = 0; p < 4; ++p)
#pragma unroll
        for (int mi = 0; mi < 2; ++mi)
#pragma unroll
            for (int ni = 0; ni < 4; ++ni)
                acc[p][mi][ni] = (f32x4){0.f, 0.f, 0.f, 0.f};

    // Prologue: tile 0 in steady-state order [B0 B1 B2 B3 A0 A2 A1 A3].
    STAGE_B(0, 0); STAGE_B(0, 1); STAGE_B(0, 2); STAGE_B(0, 3);
    STAGE_A(0, 0); STAGE_A(0, 2); STAGE_A(0, 1); STAGE_A(0, 3);

    const int Bro = (wc * 64 + r15) * 128;       // B row byte base in slot
    const int ch0 = (g4 ^ swz) * 16;             // kk=0 chunk byte
    const int ch1 = ((4 + g4) ^ swz) * 16;       // kk=1 chunk byte
    const int AroB = wr * 128 + r15;             // A row base (rows)

#define LOAD_AF(AF, Ab, P)                                                  \
    _Pragma("unroll")                                                       \
    for (int mi = 0; mi < 2; ++mi) {                                        \
        const int Aro_ = (AroB + (P) * 32 + mi * 16) * 128;                 \
        AF[mi][0] = *(const bf16x8*)((Ab) + Aro_ + ch0);                    \
        AF[mi][1] = *(const bf16x8*)((Ab) + Aro_ + ch1);                    \
    }

#define MFMA_PHASE(P, AF)                                                   \
    __builtin_amdgcn_s_setprio(1);                                          \
    _Pragma("unroll")                                                       \
    for (int mi = 0; mi < 2; ++mi)                                          \
      _Pragma("unroll")                                                     \
      for (int ni = 0; ni < 4; ++ni) {                                      \
        acc[P][mi][ni] = __builtin_amdgcn_mfma_f32_16x16x32_bf16(           \
            AF[mi][0], bg[ni][0], acc[P][mi][ni], 0, 0, 0);                 \
        acc[P][mi][ni] = __builtin_amdgcn_mfma_f32_16x16x32_bf16(           \
            AF[mi][1], bg[ni][1], acc[P][mi][ni], 0, 0, 0);                 \
      }                                                                     \
    __builtin_amdgcn_s_setprio(0);

#pragma unroll 2
    for (int kt = 0; kt < 16; ++kt) {
        const char* Ab = (const char*)As[kt & 1];
        const char* Bb = (const char*)Bs[kt & 1];
        bf16x8 bg[4][2], af0[2][2], af1[2][2];

        // ======== half-tile 0 : quadrants 0,1 ========
        // gate: B rounds 0-3 + A rounds 0,2 of tile kt landed (6 oldest)
        asm volatile("s_waitcnt vmcnt(2)" ::: "memory");
        __builtin_amdgcn_s_barrier();
        __builtin_amdgcn_sched_barrier(0);
        // group 1: reads MFMA ph0 depends on (B + A ph0) — 12 ds_reads
#pragma unroll
        for (int ni = 0; ni < 4; ++ni) {
            bg[ni][0] = *(const bf16x8*)(Bb + Bro + ni * 2048 + ch0);
            bg[ni][1] = *(const bf16x8*)(Bb + Bro + ni * 2048 + ch1);
        }
        LOAD_AF(af0, Ab, 0)
        __builtin_amdgcn_sched_barrier(0);
        // group 2: ph1's A reads — complete under ph0's MFMA burst
        LOAD_AF(af1, Ab, 1)
        __builtin_amdgcn_sched_barrier(0);
        if (kt < 15) { STAGE_B(kt + 1, 0); STAGE_B(kt + 1, 1); }
        __builtin_amdgcn_sched_barrier(0);
        MFMA_PHASE(0, af0)
        if (kt < 15) { STAGE_B(kt + 1, 2); STAGE_B(kt + 1, 3); }
        __builtin_amdgcn_sched_barrier(0);
        MFMA_PHASE(1, af1)

        // ======== half-tile 1 : quadrants 2,3 ========
        // gate: A rounds 1,3 of tile kt landed (newest 4 = B01,B23 of kt+1)
        if (kt < 15) { asm volatile("s_waitcnt vmcnt(4)" ::: "memory"); }
        else         { asm volatile("s_waitcnt vmcnt(0)" ::: "memory"); }
        __builtin_amdgcn_s_barrier();
        __builtin_amdgcn_sched_barrier(0);
        LOAD_AF(af0, Ab, 2)
        __builtin_amdgcn_sched_barrier(0);
        LOAD_AF(af1, Ab, 3)
        __builtin_amdgcn_sched_barrier(0);
        if (kt < 15) { STAGE_A(kt + 1, 0); STAGE_A(kt + 1, 2); }
        __builtin_amdgcn_sched_barrier(0);
        MFMA_PHASE(2, af0)
        if (kt < 15) { STAGE_A(kt + 1, 1); STAGE_A(kt + 1, 3); }
        __builtin_amdgcn_sched_barrier(0);
        MFMA_PHASE(3, af1)
    }
#undef STAGE_A
#undef STAGE_B
#undef LOAD_AF
#undef MFMA_PHASE

    // Fused reduction per 64x64 (b,t) cell. C/D: col=lane&15, row=(lane>>4)*4+reg.
#pragma unroll
    for (int h = 0; h < 2; ++h) {
        float cm[4];
#pragma unroll
        for (int ni = 0; ni < 4; ++ni) {
            float m = acc[h * 2][0][ni][0];
#pragma unroll
            for (int pp = 0; pp < 2; ++pp)
#pragma unroll
                for (int mi = 0; mi < 2; ++mi)
#pragma unroll
                    for (int r = 0; r < 4; ++r)
                        m = fmaxf(m, acc[h * 2 + pp][mi][ni][r]);
            m = fmaxf(m, __shfl_xor(m, 16));
            m = fmaxf(m, __shfl_xor(m, 32));
            cm[ni] = m;
        }
        float s = cm[0] + cm[1] + cm[2] + cm[3];
        s += __shfl_xor(s, 1);
        s += __shfl_xor(s, 2);
        s += __shfl_xor(s, 4);
        s += __shfl_xor(s, 8);
        if (lane == 0) {
            int b = tm * 4 + wr * 2 + h;
            int t = tn * 4 + wc;
            aggr[b * 128 + t] = s;
        }
    }
}

// ---------------------------------------------------------------------------
__global__ void loss_kernel(const float* __restrict__ aggr, float* __restrict__ out)
{
    __shared__ float red[128];
    const int x = threadIdx.x;
    const float diag = aggr[x * 128 + x];
    float mrow = 0.f, mcol = 0.f;
    for (int y = 0; y < 128; ++y) {
        if (y == x) continue;
        float a_xy = aggr[x * 128 + y];
        float a_yx = aggr[y * 128 + x];
        mrow = fmaxf(mrow, 0.2f + a_xy - diag);
        mcol = fmaxf(mcol, 0.2f + a_yx - diag);
    }
    red[x] = mrow + mcol;
    __syncthreads();
    if (x == 0) {
        float s = 0.f;
        for (int i = 0; i < 128; ++i) s += red[i];
        *out = s;
    }
}

// ---------------------------------------------------------------------------
extern "C" void kernel_launch(void* const* d_in, const int* in_sizes, int n_in,
                              void* d_out, int out_size, void* d_ws, size_t ws_size,
                              hipStream_t stream)
{
    const float* im_set = (const float*)d_in[0];
    const float* s_seq  = (const float*)d_in[1];
    const int*   im_len = (const int*)d_in[2];
    const int*   s_len  = (const int*)d_in[3];
    float* out = (float*)d_out;

    unsigned short* Abf = (unsigned short*)d_ws;                           // 16 MiB
    unsigned short* Bbf = (unsigned short*)((char*)d_ws + (16u << 20));    // 16 MiB
    float*          agg = (float*)((char*)d_ws + (32u << 20));             // 64 KiB

    conv_kernel<<<16384, 256, 0, stream>>>(im_set, im_len, s_seq, s_len, Abf, Bbf);

    gemm_aggr_kernel<<<dim3(32, 32), 512, 0, stream>>>(Abf, Bbf, agg);

    loss_kernel<<<1, 128, 0, stream>>>(agg, out);
}